// Round 10
// baseline (5790.065 us; speedup 1.0000x reference)
//
#include <hip/hip_runtime.h>

#define NN   4096
#define TT   17
#define PP   16
#define NTOT (NN*TT)          // 69632
#define NIT  47               // reference CG_ITERS (fixed)
#define KSL  1024             // k-slice per block (4 k-blocks)
#define NKB  4
#define NGB  1024             // 256 row-blocks x 4 k-blocks

// ws float offsets
#define O_PART 0               // [1024][64]: del at +0..16, gam at +32..48
#define O_SC   (NGB*64)        // scale[0..16], rhs[32..48]
#define O_ALBE (O_SC + 64)     // alpha[0..16], beta[32..48]
#define O_APGP (O_ALBE + 64)   // aprev[0..16], gprev[32..48]
#define O_R    (O_APGP + 64)
#define O_P    (O_R + NTOT)
#define O_S    (O_P + NTOT)
#define O_X    (O_S + NTOT)
#define O_W0   (O_X + NTOT)    // 4 k-split partials of K@r, each NTOT

// ---- setup: per-column sum of squares of [y | Z] ----
__global__ void k_ssq(const float* __restrict__ y, const float* __restrict__ Z,
                      float* __restrict__ ws) {
    __shared__ float red[TT];
    int t = threadIdx.x;
    if (t < TT) red[t] = 0.f;
    __syncthreads();
    int n = blockIdx.x*256 + t;
    atomicAdd(&red[0], y[n]*y[n]);
    #pragma unroll
    for (int j = 0; j < PP; ++j) { float v = Z[n*PP + j]; atomicAdd(&red[j+1], v*v); }
    __syncthreads();
    if (t < TT) ws[O_PART + blockIdx.x*64 + t] = red[t];
}

// ---- setup: scale / rhs-norm per column ----
__global__ void k_scale(float* __restrict__ ws) {
    int t = threadIdx.x;
    if (t < TT) {
        float s = 0.f;
        #pragma unroll
        for (int i = 0; i < 16; ++i) s += ws[O_PART + i*64 + t];
        float scale, rh;
        if (t == 0) {
            rh = sqrtf(s); if (rh < 1e-10f) rh = 1.f;
            scale = 1.f/rh;
        } else {
            float zn = sqrtf(s);
            float bn = zn/(zn + 1e-10f);
            rh = (bn < 1e-10f) ? 1.f : bn;
            scale = 1.f/((zn + 1e-10f)*rh);
        }
        ws[O_SC + t] = scale; ws[O_SC + 32 + t] = rh;
    }
}

// ---- setup: r0 = b_norm ([c][n] layout), zero p,s,x ----
__global__ void k_init(const float* __restrict__ y, const float* __restrict__ Z,
                       float* __restrict__ ws) {
    int e = blockIdx.x*256 + threadIdx.x;     // 272*256 == NTOT exactly
    int c = e >> 12, n = e & (NN-1);
    float raw = (c == 0) ? y[n] : Z[n*PP + (c-1)];
    ws[O_R + e] = raw * ws[O_SC + c];
    ws[O_P + e] = 0.f; ws[O_S + e] = 0.f; ws[O_X + e] = 0.f;
}

// ---- per-iter GEMM: deep-MLP version. 256 thr, 16 rows, KSL=1024.
//      Each wave bursts its FULL K working set (16 float4 = 16 KB) into
//      64 registers upfront -> ~128 KB in flight per CU. 68 KB LDS ->
//      2 blocks/CU; __launch_bounds__(256,2) -> 256-VGPR budget (R7/R9
//      verified: 2nd arg is min BLOCKS/CU). ----
__global__ __launch_bounds__(256, 2)
void k_gemm(const float* __restrict__ Km, float* __restrict__ ws) {
    const int t    = threadIdx.x, b = blockIdx.x;
    const int lane = t & 63, w = t >> 6;      // 4 waves
    const int rb   = b >> 2, kb = b & 3;      // 256 row-blocks x 4 k-blocks
    const int row0 = rb*16 + w*4;             // 4 rows per wave

    const float* r_ = ws + O_R;
    float* wp = ws + O_W0 + kb*NTOT;

    __shared__ float rl[TT*KSL];              // [c][k], 68 KB; reused for reduce
    __shared__ float redd[TT], redg[TT];

    // ---- burst-load ALL K for this wave: 16 independent dwordx4 ----
    const float* Kb = Km + (size_t)row0*NN + kb*KSL + 4*lane;
    float4 kreg[4][4];                        // [row][chunk]
    #pragma unroll
    for (int rr = 0; rr < 4; ++rr)
        #pragma unroll
        for (int ch = 0; ch < 4; ++ch)
            kreg[rr][ch] = *(const float4*)(Kb + rr*NN + ch*256);

    if (t < TT) { redd[t] = 0.f; redg[t] = 0.f; }
    // stage r slice to LDS (17 independent float4 loads per thread)
    {
        int kq = (t & 255) << 2;
        #pragma unroll
        for (int c = 0; c < TT; ++c)
            *(float4*)(rl + c*KSL + kq) = *(const float4*)(r_ + c*NN + kb*KSL + kq);
    }
    __syncthreads();

    float acc[4][TT];
    #pragma unroll
    for (int rr = 0; rr < 4; ++rr)
        #pragma unroll
        for (int c = 0; c < TT; ++c) acc[rr][c] = 0.f;

    #pragma unroll
    for (int ch = 0; ch < 4; ++ch) {          // 4 chunks x 256 k, K already in regs
        const float* rlc = rl + ch*256 + 4*lane;
        #pragma unroll
        for (int c = 0; c < TT; ++c) {
            float4 rv = *(const float4*)(rlc + c*KSL);
            #pragma unroll
            for (int rr = 0; rr < 4; ++rr)
                acc[rr][c] += kreg[rr][ch].x*rv.x + kreg[rr][ch].y*rv.y
                            + kreg[rr][ch].z*rv.z + kreg[rr][ch].w*rv.w;
        }
    }

    // partial butterfly: 64 -> 16 lane-classes
    #pragma unroll
    for (int rr = 0; rr < 4; ++rr)
        #pragma unroll
        for (int c = 0; c < TT; ++c) {
            float v = acc[rr][c];
            v += __shfl_xor(v, 32, 64);
            v += __shfl_xor(v, 16, 64);
            acc[rr][c] = v;
        }

    __syncthreads();                          // all waves done reading rl
    float4* part2 = (float4*)rl;              // reuse: [w][c] rows of 17 float4 (pad=17)
    if (lane < 16) {
        #pragma unroll
        for (int c = 0; c < TT; ++c)
            part2[(w*TT + c)*17 + lane] =
                make_float4(acc[0][c], acc[1][c], acc[2][c], acc[3][c]);
    }
    __syncthreads();

    if (t < 4*TT) {                           // 68 finish threads
        int w2 = t / TT, c2 = t % TT;
        float4 s = make_float4(0.f, 0.f, 0.f, 0.f);
        #pragma unroll
        for (int i = 0; i < 16; ++i) {
            float4 u = part2[(w2*TT + c2)*17 + i];
            s.x += u.x; s.y += u.y; s.z += u.z; s.w += u.w;
        }
        int row = rb*16 + w2*4;
        *(float4*)(wp + c2*NN + row) = s;     // dwordx4 partial write
        float4 rv = *(const float4*)(r_ + c2*NN + row);
        float dp = rv.x*s.x + rv.y*s.y + rv.z*s.z + rv.w*s.w;
        float gp = rv.x*rv.x + rv.y*rv.y + rv.z*rv.z + rv.w*rv.w;
        atomicAdd(&redd[c2], dp);
        if (kb == 0) atomicAdd(&redg[c2], gp);
    }
    __syncthreads();
    if (t < TT) {
        ws[O_PART + b*64 + t]      = redd[t];
        ws[O_PART + b*64 + 32 + t] = (kb == 0) ? redg[t] : 0.f;
    }
}

// ---- per-iter: reduce 1024 partial slots, compute alpha/beta (pipelined CG) ----
__global__ void k_red(const float* __restrict__ noise, float* __restrict__ ws, int it) {
    __shared__ float sm[8][64];
    int t = threadIdx.x, seg = t >> 6, j = t & 63;   // 512 threads, 8 segments
    float s = 0.f;
    if (j < TT || (j >= 32 && j < 32 + TT)) {
        for (int i = 0; i < NGB/8; ++i)
            s += ws[O_PART + (seg*(NGB/8) + i)*64 + j];
    }
    sm[seg][j] = s;
    __syncthreads();
    if (t < TT) {
        float del = 0.f, gam = 0.f;
        #pragma unroll
        for (int g = 0; g < 8; ++g) { del += sm[g][t]; gam += sm[g][32 + t]; }
        float s2 = noise[0]*noise[0];
        float delta = del + s2*gam;               // r^T (K + s2 I) r
        float beta = 0.f, D = delta;
        if (it > 0) {
            float gp = ws[O_APGP + 32 + t];
            beta = (fabsf(gp) < 1e-30f) ? 0.f : gam/gp;
            float ap = ws[O_APGP + t];
            D = delta - ((fabsf(ap) < 1e-30f) ? 0.f : beta*gam/ap);
        }
        float alpha = (fabsf(D) < 1e-30f) ? 0.f : gam/D;
        ws[O_ALBE + t] = alpha; ws[O_ALBE + 32 + t] = beta;
        ws[O_APGP + t] = alpha; ws[O_APGP + 32 + t] = gam;
    }
}

// ---- per-iter: element-wise p,s,x,r updates (fully coalesced, [c][n] linear) ----
__global__ void k_upd(const float* __restrict__ noise, float* __restrict__ ws,
                      float* __restrict__ out, int last) {
    int e = blockIdx.x*256 + threadIdx.x;     // 272*256 == NTOT
    int c = e >> 12, n = e & (NN-1);
    float s2 = noise[0]*noise[0];
    float al = ws[O_ALBE + c], be = ws[O_ALBE + 32 + c];
    float rv = ws[O_R + e];
    float wv = ws[O_W0 + e] + ws[O_W0 + NTOT + e]
             + ws[O_W0 + 2*NTOT + e] + ws[O_W0 + 3*NTOT + e] + s2*rv;
    float pn = rv + be*ws[O_P + e];
    float sn = wv + be*ws[O_S + e];
    float xn = ws[O_X + e] + al*pn;
    float rn = rv - al*sn;
    ws[O_P + e] = pn; ws[O_S + e] = sn; ws[O_X + e] = xn; ws[O_R + e] = rn;
    if (last) out[n*TT + c] = xn * ws[O_SC + 32 + c];
}

extern "C" void kernel_launch(void* const* d_in, const int* in_sizes, int n_in,
                              void* d_out, int out_size, void* d_ws, size_t ws_size,
                              hipStream_t stream) {
    const float* Km    = (const float*)d_in[0];
    const float* yv    = (const float*)d_in[1];
    const float* Zm    = (const float*)d_in[2];
    const float* noise = (const float*)d_in[3];
    float* out = (float*)d_out;
    float* ws  = (float*)d_ws;

    k_ssq  <<<16, 256, 0, stream>>>(yv, Zm, ws);
    k_scale<<<1,   64, 0, stream>>>(ws);
    k_init <<<272, 256, 0, stream>>>(yv, Zm, ws);
    for (int it = 0; it < NIT; ++it) {
        k_gemm<<<NGB, 256, 0, stream>>>(Km, ws);
        k_red <<<1,   512, 0, stream>>>(noise, ws, it);
        k_upd <<<272, 256, 0, stream>>>(noise, ws, out, it == NIT-1);
    }
}